// Round 9
// baseline (1010.162 us; speedup 1.0000x reference)
//
#include <hip/hip_runtime.h>
#include <stdint.h>

// Problem constants
#define BB 4
#define LL 2048
#define QQ 16293
#define RR 24
#define DD 32
#define SS 128
#define NLAYER 8
#define OUTW 1792
#define TT0 2047              // length of x after embedding (L-1)
#define MROWS (BB*OUTW)       // 7168
#define NPAD 16384            // padded Q for GEMM tiles
#define WCH 28                // skip rows per fused-layer block (64 blocks/batch)
#define STRIPW 2048           // GEMM: cols per block strip
#define NSTRIP 8              // 8*2048 = 16384 = NPAD (aligns strips to XCDs)

typedef float v4f __attribute__((ext_vector_type(4)));
typedef short v8s __attribute__((ext_vector_type(8)));

static __device__ __forceinline__ unsigned short f2bf(float x) {
  unsigned int u = __float_as_uint(x);
  unsigned int r = (u + 0x7fffu + ((u >> 16) & 1u)) >> 16;
  return (unsigned short)r;
}

static __device__ __forceinline__ float fast_sigmoid(float z) {
  return __builtin_amdgcn_rcpf(1.0f + __expf(-z));
}
static __device__ __forceinline__ float fast_tanh(float z) {
  return 1.0f - 2.0f * __builtin_amdgcn_rcpf(1.0f + __expf(2.0f * z));
}

// ---------------------------------------------------------------------------
// Fused: embedding + 8 WaveNet layers + skip accumulation. (unchanged)
// Grid (64, B), block 1024 = 16 waves.
// ---------------------------------------------------------------------------
__global__ __launch_bounds__(1024) void fused_layers_kernel(
    const int* __restrict__ idx, const float* __restrict__ preW,
    const float* __restrict__ filtW, const float* __restrict__ gateW,
    const float* __restrict__ resW, const float* __restrict__ skipW,
    float* __restrict__ skip_out) {
  int b = blockIdx.y;
  int j0 = blockIdx.x * WCH;
  int lane = (int)(threadIdx.x & 63);
  int w = __builtin_amdgcn_readfirstlane((int)(threadIdx.x >> 6));

  __shared__ float x_t[2][RR][66];   // col-major: x_t[buf][r][l]
  __shared__ float out_s[64][33];

  for (int z = (int)threadIdx.x; z < 2 * RR * 2; z += 1024) {
    int bu = z & 1;
    int cc = 64 + ((z >> 1) & 1);
    int r = z >> 2;
    x_t[bu][r][cc] = 0.f;
  }

  int tbase = j0 + 247;
  if (w < 12) {
    int t = tbase + lane;
    if (t > TT0 - 1) t = TT0 - 1;
    int i0 = idx[b * LL + t];
    int i1 = idx[b * LL + t + 1];
    const float* p0 = preW + (size_t)i0 * RR + 2 * w;
    const float* p1 = preW + (size_t)QQ * RR + (size_t)i1 * RR + 2 * w;
#pragma unroll
    for (int rr = 0; rr < 2; ++rr)
      x_t[0][2 * w + rr][lane] = p0[rr] + p1[rr];
  }

  float sk[8];
#pragma unroll
  for (int c = 0; c < 8; ++c) sk[c] = 0.f;

  __syncthreads();

  for (int i = 0; i < NLAYER; ++i) {
    int cur = i & 1, nxt = cur ^ 1;
    int lmax = 62 - i;

    float xa[RR], xb[RR];
#pragma unroll
    for (int r = 0; r < RR; ++r) {
      xa[r] = x_t[cur][r][lane];
      xb[r] = x_t[cur][r][lane + 1];
    }
    const float* Fw = filtW + (size_t)i * 2 * RR * DD;
    const float* Gw = gateW + (size_t)i * 2 * RR * DD;
    float zf[2], zg[2];
#pragma unroll
    for (int dd = 0; dd < 2; ++dd) { zf[dd] = 0.f; zg[dd] = 0.f; }
#pragma unroll
    for (int r = 0; r < RR; ++r) {
#pragma unroll
      for (int dd = 0; dd < 2; ++dd) {
        int d = w * 2 + dd;
        zf[dd] = fmaf(xa[r], Fw[r * DD + d], zf[dd]);
        zf[dd] = fmaf(xb[r], Fw[RR * DD + r * DD + d], zf[dd]);
        zg[dd] = fmaf(xa[r], Gw[r * DD + d], zg[dd]);
        zg[dd] = fmaf(xb[r], Gw[RR * DD + r * DD + d], zg[dd]);
      }
    }
    if (lane <= lmax) {
#pragma unroll
      for (int dd = 0; dd < 2; ++dd)
        out_s[lane][w * 2 + dd] = fast_tanh(zf[dd]) * fast_sigmoid(zg[dd]);
    }
    __syncthreads();

    if (lane < WCH) {
      const float* Sw = skipW + (size_t)i * DD * SS + w * 8;
#pragma unroll
      for (int d = 0; d < DD; ++d) {
        float o = out_s[lane + 7 - i][d];
#pragma unroll
        for (int c = 0; c < 8; ++c)
          sk[c] = fmaf(o, Sw[d * SS + c], sk[c]);
      }
    }

    if (w < 12 && lane <= lmax) {
      const float* Rw = resW + (size_t)i * DD * RR;
#pragma unroll
      for (int rr = 0; rr < 2; ++rr) {
        int r = w * 2 + rr;
        float acc = x_t[cur][r][lane + 1];
#pragma unroll
        for (int d = 0; d < DD; ++d)
          acc = fmaf(out_s[lane][d], Rw[d * RR + r], acc);
        x_t[nxt][r][lane] = acc;
      }
    }
    __syncthreads();
  }

  if (lane < WCH) {
    float* sp = skip_out + ((size_t)b * OUTW + j0 + lane) * SS + w * 8;
#pragma unroll
    for (int c4 = 0; c4 < 2; ++c4) {
      float4 v;
      v.x = sk[4 * c4 + 0]; v.y = sk[4 * c4 + 1];
      v.z = sk[4 * c4 + 2]; v.w = sk[4 * c4 + 3];
      *(float4*)(sp + 4 * c4) = v;
    }
  }
}

// ---------------------------------------------------------------------------
// h1 = relu(relu(skip_sum) @ post_W1), stored bf16  [7168][128] (unchanged)
// ---------------------------------------------------------------------------
__global__ __launch_bounds__(256) void h1_kernel(const float* __restrict__ skip_sum,
                                                 const float* __restrict__ W1,
                                                 unsigned short* __restrict__ h1) {
  int m0 = blockIdx.x * 32;
  int tc = threadIdx.x & 31;
  int tr = threadIdx.x >> 5;
  __shared__ float h_s[32][128];
#pragma unroll
  for (int it = 0; it < 16; ++it) {
    int lin = it * 256 + (int)threadIdx.x;
    int rrow = lin >> 7, d = lin & 127;
    float v = skip_sum[(size_t)(m0 + rrow) * SS + d];
    h_s[rrow][d] = v > 0.f ? v : 0.f;
  }
  __syncthreads();

  float acc[4][4];
#pragma unroll
  for (int rr = 0; rr < 4; ++rr)
#pragma unroll
    for (int c = 0; c < 4; ++c) acc[rr][c] = 0.f;

#pragma unroll 4
  for (int d = 0; d < 128; ++d) {
    float4 wv = *(const float4*)(W1 + (size_t)d * SS + tc * 4);
#pragma unroll
    for (int rr = 0; rr < 4; ++rr) {
      float hv = h_s[tr * 4 + rr][d];
      acc[rr][0] = fmaf(hv, wv.x, acc[rr][0]);
      acc[rr][1] = fmaf(hv, wv.y, acc[rr][1]);
      acc[rr][2] = fmaf(hv, wv.z, acc[rr][2]);
      acc[rr][3] = fmaf(hv, wv.w, acc[rr][3]);
    }
  }
#pragma unroll
  for (int rr = 0; rr < 4; ++rr) {
    int row = m0 + tr * 4 + rr;
    ushort4 u;
    u.x = f2bf(fmaxf(acc[rr][0], 0.f));
    u.y = f2bf(fmaxf(acc[rr][1], 0.f));
    u.z = f2bf(fmaxf(acc[rr][2], 0.f));
    u.w = f2bf(fmaxf(acc[rr][3], 0.f));
    *(ushort4*)(h1 + (size_t)row * SS + tc * 4) = u;
  }
}

// ---------------------------------------------------------------------------
// W2T: transpose post_W2 [128][16293] -> bf16 [16384][128], zero-padded
// ---------------------------------------------------------------------------
__global__ __launch_bounds__(256) void w2t_kernel(const float* __restrict__ W2,
                                                  unsigned short* __restrict__ W2T) {
  int n0 = blockIdx.x * 64;
  __shared__ float t_s[64][129];
#pragma unroll
  for (int it = 0; it < 32; ++it) {
    int lin = it * 256 + (int)threadIdx.x;
    int k = lin >> 6, nn = lin & 63;
    int n = n0 + nn;
    t_s[nn][k] = (n < QQ) ? W2[(size_t)k * QQ + n] : 0.f;
  }
  __syncthreads();
#pragma unroll
  for (int it = 0; it < 4; ++it) {
    int lin = it * 256 + (int)threadIdx.x;
    int nn = lin >> 4, slot = lin & 15;
    v8s val;
#pragma unroll
    for (int jj = 0; jj < 8; ++jj) val[jj] = (short)f2bf(t_s[nn][slot * 8 + jj]);
    *(v8s*)(W2T + ((size_t)(n0 + nn)) * 128 + slot * 8) = val;
  }
}

// ---------------------------------------------------------------------------
// logits = h1 @ W2  (bf16 MFMA, fp32 accum).  M=7168, N=16384(pad), K=128.
// v5: write-locality tiling. Grid (8 strips, 224 m-blocks); block owns
// 32m x 2048n, walks 16 chunks of 128 cols left->right => each row written
// as sequential ~8KB runs (16x v1's 512B run length; DRAM page locality).
// blockIdx.x = strip => strip s pins to XCD s (id%8): B-strip (512KB) stays
// L2-resident per XCD. A resident in VGPRs (K=128); B chunk LDS-staged
// (v1's swizzled path); C transposed via c_s[32][129] (<=4-way conflicts);
// nt v4f stores (v1's best instruction form).
// ---------------------------------------------------------------------------
struct GemmSh {
  union {
    unsigned short B_s[128 * 128];   // 32KB
    float c_s[32][129];              // 16.5KB
  } u;
};

__global__ __launch_bounds__(256) void gemm_kernel(const unsigned short* __restrict__ A,
                                                   const unsigned short* __restrict__ Bm,
                                                   float* __restrict__ Cc) {
  __shared__ GemmSh sh;
  int strip = blockIdx.x;
  int m0 = blockIdx.y * 32;
  int tid = threadIdx.x;
  int lane = tid & 63;
  int w = tid >> 6;
  int lr = lane & 15, g = lane >> 4;

  // ---- A fragments resident for whole block: [mf][ks], rows m0..m0+31
  v8s a[2][4];
#pragma unroll
  for (int mf = 0; mf < 2; ++mf)
#pragma unroll
    for (int ks = 0; ks < 4; ++ks)
      a[mf][ks] = *(const v8s*)(A + ((size_t)(m0 + mf * 16 + lr)) * 128 + (ks * 4 + g) * 8);

  int srow = tid >> 3;   // store-phase row 0..31
  int sp = tid & 7;      // store-phase col group (16 cols)

#pragma unroll 1
  for (int c = 0; c < 16; ++c) {
    int nb = strip * STRIPW + c * 128;

    // ---- stage B chunk [128n][128k] with XOR swizzle
#pragma unroll
    for (int it = 0; it < 8; ++it) {
      int lin = it * 256 + tid;
      int row = lin >> 4, slot = lin & 15;
      int sw = slot ^ (row & 7);
      uint4 vb = *(const uint4*)(Bm + ((size_t)(nb + row)) * 128 + slot * 8);
      *(uint4*)(sh.u.B_s + row * 128 + sw * 8) = vb;
    }
    __syncthreads();

    v4f acc[2][2];
#pragma unroll
    for (int mf = 0; mf < 2; ++mf)
#pragma unroll
      for (int nf = 0; nf < 2; ++nf) {
        v4f z = {0.f, 0.f, 0.f, 0.f};
        acc[mf][nf] = z;
      }

#pragma unroll
    for (int ks = 0; ks < 4; ++ks) {
      int kg = ks * 4 + g;
      v8s b[2];
#pragma unroll
      for (int nf = 0; nf < 2; ++nf) {
        int row = w * 32 + nf * 16 + lr;
        b[nf] = *(v8s*)(sh.u.B_s + row * 128 + ((kg ^ (row & 7)) * 8));
      }
#pragma unroll
      for (int mf = 0; mf < 2; ++mf)
#pragma unroll
        for (int nf = 0; nf < 2; ++nf)
          acc[mf][nf] = __builtin_amdgcn_mfma_f32_16x16x32_bf16(a[mf][ks], b[nf], acc[mf][nf], 0, 0, 0);
    }
    __syncthreads();   // B_s reads done (c_s aliases it)

    // ---- transpose through LDS
#pragma unroll
    for (int mf = 0; mf < 2; ++mf)
#pragma unroll
      for (int reg = 0; reg < 4; ++reg)
#pragma unroll
        for (int nf = 0; nf < 2; ++nf)
          sh.u.c_s[mf * 16 + g * 4 + reg][w * 32 + nf * 16 + lr] = acc[mf][nf][reg];
    __syncthreads();

    // ---- coalesced nt stores: per row, 8 threads cover 128 contiguous cols
    float* crow = Cc + (size_t)(m0 + srow) * QQ;
    if (nb + 128 <= QQ) {
#pragma unroll
      for (int e = 0; e < 4; ++e) {
        int col = sp * 16 + e * 4;
        v4f v;
        v[0] = sh.u.c_s[srow][col + 0];
        v[1] = sh.u.c_s[srow][col + 1];
        v[2] = sh.u.c_s[srow][col + 2];
        v[3] = sh.u.c_s[srow][col + 3];
        __builtin_nontemporal_store(v, (v4f*)(crow + nb + col));
      }
    } else {
#pragma unroll
      for (int j = 0; j < 16; ++j) {
        int n = nb + sp * 16 + j;
        if (n < QQ) crow[n] = sh.u.c_s[srow][sp * 16 + j];
      }
    }
    __syncthreads();   // c_s reads done before next stage overwrites
  }
}

// ---------------------------------------------------------------------------
extern "C" void kernel_launch(void* const* d_in, const int* in_sizes, int n_in,
                              void* d_out, int out_size, void* d_ws, size_t ws_size,
                              hipStream_t stream) {
  (void)in_sizes; (void)n_in; (void)out_size; (void)ws_size;
  const int*   idx   = (const int*)d_in[0];
  const float* preW  = (const float*)d_in[1];
  const float* filtW = (const float*)d_in[2];
  const float* gateW = (const float*)d_in[3];
  const float* resW  = (const float*)d_in[4];
  const float* skipW = (const float*)d_in[5];
  const float* W1    = (const float*)d_in[6];
  const float* W2    = (const float*)d_in[7];
  float* out = (float*)d_out;

  char* ws = (char*)d_ws;
  float* skip = (float*)(ws);                              // 3,670,016 B
  unsigned short* h1  = (unsigned short*)(ws + 3670016);   // 1,835,008 B
  unsigned short* W2T = (unsigned short*)(ws + 5505024);   // 4,194,304 B  (~9.7 MB)

  w2t_kernel<<<dim3(NPAD / 64), 256, 0, stream>>>(W2, W2T);
  fused_layers_kernel<<<dim3(OUTW / WCH, BB), 1024, 0, stream>>>(idx, preW, filtW, gateW,
                                                                 resW, skipW, skip);
  h1_kernel<<<dim3(MROWS / 32), 256, 0, stream>>>(skip, W1, h1);
  gemm_kernel<<<dim3(NSTRIP, MROWS / 32), 256, 0, stream>>>(h1, W2T, out);
}

// Round 10
// 313.619 us; speedup vs baseline: 3.2210x; 3.2210x over previous
//
#include <hip/hip_runtime.h>
#include <stdint.h>

// Problem constants
#define BB 4
#define LL 2048
#define QQ 16293
#define RR 24
#define DD 32
#define SS 128
#define NLAYER 8
#define OUTW 1792
#define TT0 2047              // length of x after embedding (L-1)
#define MROWS (BB*OUTW)       // 7168
#define NPAD 16384            // padded Q for GEMM tiles
#define WCH 28                // skip rows per fused-layer block (64 blocks/batch)

typedef float v4f __attribute__((ext_vector_type(4)));
typedef short v8s __attribute__((ext_vector_type(8)));

static __device__ __forceinline__ unsigned short f2bf(float x) {
  unsigned int u = __float_as_uint(x);
  unsigned int r = (u + 0x7fffu + ((u >> 16) & 1u)) >> 16;
  return (unsigned short)r;
}

static __device__ __forceinline__ float fast_sigmoid(float z) {
  return __builtin_amdgcn_rcpf(1.0f + __expf(-z));
}
static __device__ __forceinline__ float fast_tanh(float z) {
  return 1.0f - 2.0f * __builtin_amdgcn_rcpf(1.0f + __expf(2.0f * z));
}

// ---------------------------------------------------------------------------
// Fused: embedding + 8 WaveNet layers + skip accumulation. (unchanged)
// Grid (64, B), block 1024 = 16 waves.
// ---------------------------------------------------------------------------
__global__ __launch_bounds__(1024) void fused_layers_kernel(
    const int* __restrict__ idx, const float* __restrict__ preW,
    const float* __restrict__ filtW, const float* __restrict__ gateW,
    const float* __restrict__ resW, const float* __restrict__ skipW,
    float* __restrict__ skip_out) {
  int b = blockIdx.y;
  int j0 = blockIdx.x * WCH;
  int lane = (int)(threadIdx.x & 63);
  int w = __builtin_amdgcn_readfirstlane((int)(threadIdx.x >> 6));

  __shared__ float x_t[2][RR][66];   // col-major: x_t[buf][r][l]
  __shared__ float out_s[64][33];

  for (int z = (int)threadIdx.x; z < 2 * RR * 2; z += 1024) {
    int bu = z & 1;
    int cc = 64 + ((z >> 1) & 1);
    int r = z >> 2;
    x_t[bu][r][cc] = 0.f;
  }

  int tbase = j0 + 247;
  if (w < 12) {
    int t = tbase + lane;
    if (t > TT0 - 1) t = TT0 - 1;
    int i0 = idx[b * LL + t];
    int i1 = idx[b * LL + t + 1];
    const float* p0 = preW + (size_t)i0 * RR + 2 * w;
    const float* p1 = preW + (size_t)QQ * RR + (size_t)i1 * RR + 2 * w;
#pragma unroll
    for (int rr = 0; rr < 2; ++rr)
      x_t[0][2 * w + rr][lane] = p0[rr] + p1[rr];
  }

  float sk[8];
#pragma unroll
  for (int c = 0; c < 8; ++c) sk[c] = 0.f;

  __syncthreads();

  for (int i = 0; i < NLAYER; ++i) {
    int cur = i & 1, nxt = cur ^ 1;
    int lmax = 62 - i;

    float xa[RR], xb[RR];
#pragma unroll
    for (int r = 0; r < RR; ++r) {
      xa[r] = x_t[cur][r][lane];
      xb[r] = x_t[cur][r][lane + 1];
    }
    const float* Fw = filtW + (size_t)i * 2 * RR * DD;
    const float* Gw = gateW + (size_t)i * 2 * RR * DD;
    float zf[2], zg[2];
#pragma unroll
    for (int dd = 0; dd < 2; ++dd) { zf[dd] = 0.f; zg[dd] = 0.f; }
#pragma unroll
    for (int r = 0; r < RR; ++r) {
#pragma unroll
      for (int dd = 0; dd < 2; ++dd) {
        int d = w * 2 + dd;
        zf[dd] = fmaf(xa[r], Fw[r * DD + d], zf[dd]);
        zf[dd] = fmaf(xb[r], Fw[RR * DD + r * DD + d], zf[dd]);
        zg[dd] = fmaf(xa[r], Gw[r * DD + d], zg[dd]);
        zg[dd] = fmaf(xb[r], Gw[RR * DD + r * DD + d], zg[dd]);
      }
    }
    if (lane <= lmax) {
#pragma unroll
      for (int dd = 0; dd < 2; ++dd)
        out_s[lane][w * 2 + dd] = fast_tanh(zf[dd]) * fast_sigmoid(zg[dd]);
    }
    __syncthreads();

    if (lane < WCH) {
      const float* Sw = skipW + (size_t)i * DD * SS + w * 8;
#pragma unroll
      for (int d = 0; d < DD; ++d) {
        float o = out_s[lane + 7 - i][d];
#pragma unroll
        for (int c = 0; c < 8; ++c)
          sk[c] = fmaf(o, Sw[d * SS + c], sk[c]);
      }
    }

    if (w < 12 && lane <= lmax) {
      const float* Rw = resW + (size_t)i * DD * RR;
#pragma unroll
      for (int rr = 0; rr < 2; ++rr) {
        int r = w * 2 + rr;
        float acc = x_t[cur][r][lane + 1];
#pragma unroll
        for (int d = 0; d < DD; ++d)
          acc = fmaf(out_s[lane][d], Rw[d * RR + r], acc);
        x_t[nxt][r][lane] = acc;
      }
    }
    __syncthreads();
  }

  if (lane < WCH) {
    float* sp = skip_out + ((size_t)b * OUTW + j0 + lane) * SS + w * 8;
#pragma unroll
    for (int c4 = 0; c4 < 2; ++c4) {
      float4 v;
      v.x = sk[4 * c4 + 0]; v.y = sk[4 * c4 + 1];
      v.z = sk[4 * c4 + 2]; v.w = sk[4 * c4 + 3];
      *(float4*)(sp + 4 * c4) = v;
    }
  }
}

// ---------------------------------------------------------------------------
// h1 = relu(relu(skip_sum) @ post_W1), stored bf16  [7168][128] (unchanged)
// ---------------------------------------------------------------------------
__global__ __launch_bounds__(256) void h1_kernel(const float* __restrict__ skip_sum,
                                                 const float* __restrict__ W1,
                                                 unsigned short* __restrict__ h1) {
  int m0 = blockIdx.x * 32;
  int tc = threadIdx.x & 31;
  int tr = threadIdx.x >> 5;
  __shared__ float h_s[32][128];
#pragma unroll
  for (int it = 0; it < 16; ++it) {
    int lin = it * 256 + (int)threadIdx.x;
    int rrow = lin >> 7, d = lin & 127;
    float v = skip_sum[(size_t)(m0 + rrow) * SS + d];
    h_s[rrow][d] = v > 0.f ? v : 0.f;
  }
  __syncthreads();

  float acc[4][4];
#pragma unroll
  for (int rr = 0; rr < 4; ++rr)
#pragma unroll
    for (int c = 0; c < 4; ++c) acc[rr][c] = 0.f;

#pragma unroll 4
  for (int d = 0; d < 128; ++d) {
    float4 wv = *(const float4*)(W1 + (size_t)d * SS + tc * 4);
#pragma unroll
    for (int rr = 0; rr < 4; ++rr) {
      float hv = h_s[tr * 4 + rr][d];
      acc[rr][0] = fmaf(hv, wv.x, acc[rr][0]);
      acc[rr][1] = fmaf(hv, wv.y, acc[rr][1]);
      acc[rr][2] = fmaf(hv, wv.z, acc[rr][2]);
      acc[rr][3] = fmaf(hv, wv.w, acc[rr][3]);
    }
  }
#pragma unroll
  for (int rr = 0; rr < 4; ++rr) {
    int row = m0 + tr * 4 + rr;
    ushort4 u;
    u.x = f2bf(fmaxf(acc[rr][0], 0.f));
    u.y = f2bf(fmaxf(acc[rr][1], 0.f));
    u.z = f2bf(fmaxf(acc[rr][2], 0.f));
    u.w = f2bf(fmaxf(acc[rr][3], 0.f));
    *(ushort4*)(h1 + (size_t)row * SS + tc * 4) = u;
  }
}

// ---------------------------------------------------------------------------
// W2T: transpose post_W2 [128][16293] -> bf16 [16384][128], zero-padded
// ---------------------------------------------------------------------------
__global__ __launch_bounds__(256) void w2t_kernel(const float* __restrict__ W2,
                                                  unsigned short* __restrict__ W2T) {
  int n0 = blockIdx.x * 64;
  __shared__ float t_s[64][129];
#pragma unroll
  for (int it = 0; it < 32; ++it) {
    int lin = it * 256 + (int)threadIdx.x;
    int k = lin >> 6, nn = lin & 63;
    int n = n0 + nn;
    t_s[nn][k] = (n < QQ) ? W2[(size_t)k * QQ + n] : 0.f;
  }
  __syncthreads();
#pragma unroll
  for (int it = 0; it < 4; ++it) {
    int lin = it * 256 + (int)threadIdx.x;
    int nn = lin >> 4, slot = lin & 15;
    v8s val;
#pragma unroll
    for (int jj = 0; jj < 8; ++jj) val[jj] = (short)f2bf(t_s[nn][slot * 8 + jj]);
    *(v8s*)(W2T + ((size_t)(n0 + nn)) * 128 + slot * 8) = val;
  }
}

// ---------------------------------------------------------------------------
// logits = h1 @ W2  (bf16 MFMA, fp32 accum).  M=7168, N=16384(pad), K=128.
// v6 = v1 (the 225us best: 128x128 tiles, LDS-staged A/B, LDS C transpose,
// 2rows x 512B per store instruction) with ONE token changed: stores are
// PLAIN v4f instead of nontemporal. Theory: nt bypasses L2 so each block's
// 512B fragments hit DRAM as isolated partial-page bursts (~2.1 TB/s);
// plain stores let L2 merge adjacent runs from co-resident same-row
// neighbor blocks (blockIdx.x = n) into full-line streams (fill: 6.8 TB/s).
// ---------------------------------------------------------------------------
struct GemmLds {
  union {
    struct { unsigned short A_s[128 * 128]; unsigned short B_s[128 * 128]; } ab;
    float c_s[128][132];
  };
};

__global__ __launch_bounds__(256) void gemm_kernel(const unsigned short* __restrict__ A,
                                                   const unsigned short* __restrict__ Bm,
                                                   float* __restrict__ Cc) {
  __shared__ GemmLds sh;
  unsigned short* A_s = sh.ab.A_s;
  unsigned short* B_s = sh.ab.B_s;
  int m0 = blockIdx.y * 128;
  int n0 = blockIdx.x * 128;
  int tid = threadIdx.x;

#pragma unroll
  for (int it = 0; it < 8; ++it) {
    int lin = it * 256 + tid;
    int row = lin >> 4, slot = lin & 15;
    int sw = slot ^ (row & 7);
    uint4 va = *(const uint4*)(A + ((size_t)(m0 + row)) * 128 + slot * 8);
    *(uint4*)(A_s + row * 128 + sw * 8) = va;
    uint4 vb = *(const uint4*)(Bm + ((size_t)(n0 + row)) * 128 + slot * 8);
    *(uint4*)(B_s + row * 128 + sw * 8) = vb;
  }
  __syncthreads();

  int lane = tid & 63;
  int w = tid >> 6;
  int wm = (w >> 1) * 64, wn = (w & 1) * 64;
  int lr = lane & 15, g = lane >> 4;

  v4f acc[4][4];
#pragma unroll
  for (int mf = 0; mf < 4; ++mf)
#pragma unroll
    for (int nf = 0; nf < 4; ++nf) {
      v4f z = {0.f, 0.f, 0.f, 0.f};
      acc[mf][nf] = z;
    }

#pragma unroll
  for (int ks = 0; ks < 4; ++ks) {
    int kg = ks * 4 + g;
    v8s a[4], bfr[4];
#pragma unroll
    for (int mf = 0; mf < 4; ++mf) {
      int row = wm + mf * 16 + lr;
      a[mf] = *(v8s*)(A_s + row * 128 + ((kg ^ (row & 7)) * 8));
    }
#pragma unroll
    for (int nf = 0; nf < 4; ++nf) {
      int row = wn + nf * 16 + lr;
      bfr[nf] = *(v8s*)(B_s + row * 128 + ((kg ^ (row & 7)) * 8));
    }
#pragma unroll
    for (int mf = 0; mf < 4; ++mf)
#pragma unroll
      for (int nf = 0; nf < 4; ++nf)
        acc[mf][nf] = __builtin_amdgcn_mfma_f32_16x16x32_bf16(a[mf], bfr[nf], acc[mf][nf], 0, 0, 0);
  }

  // ---- epilogue: acc -> LDS transpose, then PLAIN coalesced v4f stores
  __syncthreads();   // all LDS reads of A_s/B_s done
#pragma unroll
  for (int mf = 0; mf < 4; ++mf)
#pragma unroll
    for (int reg = 0; reg < 4; ++reg) {
      int row = wm + mf * 16 + g * 4 + reg;
#pragma unroll
      for (int nf = 0; nf < 4; ++nf)
        sh.c_s[row][wn + nf * 16 + lr] = acc[mf][nf][reg];
    }
  __syncthreads();

  int slot = tid & 31;            // 32 v4f-slots per 128-col row
  int rsub = tid >> 5;            // 8 rows per iteration
  bool edge = (n0 + 128 > QQ);
#pragma unroll
  for (int it = 0; it < 16; ++it) {
    int row = it * 8 + rsub;
    int n = n0 + slot * 4;
    v4f v = *(v4f*)(&sh.c_s[row][slot * 4]);
    float* crow = Cc + (size_t)(m0 + row) * QQ;
    if (!edge) {
      *(v4f*)(crow + n) = v;                 // PLAIN store (L2-mediated)
    } else {
      if (n + 3 < QQ) {
        *(v4f*)(crow + n) = v;
      } else {
        if (n + 0 < QQ) crow[n + 0] = v.x;
        if (n + 1 < QQ) crow[n + 1] = v.y;
        if (n + 2 < QQ) crow[n + 2] = v.z;
        if (n + 3 < QQ) crow[n + 3] = v.w;
      }
    }
  }
}

// ---------------------------------------------------------------------------
extern "C" void kernel_launch(void* const* d_in, const int* in_sizes, int n_in,
                              void* d_out, int out_size, void* d_ws, size_t ws_size,
                              hipStream_t stream) {
  (void)in_sizes; (void)n_in; (void)out_size; (void)ws_size;
  const int*   idx   = (const int*)d_in[0];
  const float* preW  = (const float*)d_in[1];
  const float* filtW = (const float*)d_in[2];
  const float* gateW = (const float*)d_in[3];
  const float* resW  = (const float*)d_in[4];
  const float* skipW = (const float*)d_in[5];
  const float* W1    = (const float*)d_in[6];
  const float* W2    = (const float*)d_in[7];
  float* out = (float*)d_out;

  char* ws = (char*)d_ws;
  float* skip = (float*)(ws);                              // 3,670,016 B
  unsigned short* h1  = (unsigned short*)(ws + 3670016);   // 1,835,008 B
  unsigned short* W2T = (unsigned short*)(ws + 5505024);   // 4,194,304 B  (~9.7 MB)

  w2t_kernel<<<dim3(NPAD / 64), 256, 0, stream>>>(W2, W2T);
  fused_layers_kernel<<<dim3(OUTW / WCH, BB), 1024, 0, stream>>>(idx, preW, filtW, gateW,
                                                                 resW, skipW, skip);
  h1_kernel<<<dim3(MROWS / 32), 256, 0, stream>>>(skip, W1, h1);
  gemm_kernel<<<dim3(NPAD / 128, MROWS / 128), 256, 0, stream>>>(h1, W2T, out);
}